// Round 2
// baseline (2077.346 us; speedup 1.0000x reference)
//
#include <hip/hip_runtime.h>
#include <math.h>

// ---------------------------------------------------------------------------
// GP posterior mean via separable NUFFT outer products + 128x128 circulant
// embedding (exact linear conv == reference's 127-circular) + 50-iter CG.
// Accumulation over N=100k points in fp32 (error ~1e-7 rel); everything
// downstream (Vf, CG, eval) in fp64 to track the np/fp64 CG trajectory.
// ---------------------------------------------------------------------------

#define CV 102   // chunks per v-tile kind (2 kinds)
#define CF 51    // chunks for Fy kind
#define NBLK (2*CV + CF)   // 255
#define PB 16    // points per staging batch

__device__ inline void cmac(float2& acc, float2 a, float2 b) {
    acc.x += a.x * b.x - a.y * b.y;
    acc.y += a.x * b.y + a.y * b.x;
}
__device__ inline void dmac(double2& acc, double2 a, double2 b) {
    acc.x = fma(a.x, b.x, fma(-a.y, b.y, acc.x));
    acc.y = fma(a.x, b.y, fma(a.y, b.x, acc.y));
}
__device__ inline void dmacc(double2& acc, double2 a, double2 b) {  // acc += a*conj(b)
    acc.x = fma(a.x, b.x, fma(a.y, b.y, acc.x));
    acc.y = fma(a.y, b.x, fma(-a.x, b.y, acc.y));
}

// fp32 phase with fp64 angle reduction: exp(i*pi*(x*m))
__device__ inline float2 phasef(float xval, float m) {
    double ang = (double)xval * (double)m;
    double r = ang - 2.0 * rint(ang * 0.5);
    float sn, cs;
    sincospif((float)r, &sn, &cs);
    return make_float2(cs, sn);
}

// ---------------------------------------------------------------------------
// Kernel A: accumulate v (127x127 -> circulant-embedded vc 128x128, fp64) and
// Fy (64x64 fp64, y-weighted) over all points. fp32 per-block partials.
// v[a,b]  = sum_n exp(i pi x0 (a-63)) exp(i pi x1 (b-63))
// Fy[a,b] = sum_n y_n exp(i pi x0 (32-a)) exp(i pi x1 (32-b))
// ---------------------------------------------------------------------------
__global__ __launch_bounds__(256) void k_outer(const float* __restrict__ x,
                                               const float* __restrict__ y,
                                               double2* __restrict__ vc,
                                               double2* __restrict__ fy, int N)
{
    __shared__ float2 hs[PB][192];
    __shared__ float xs1[PB], xs2[PB], yv[PB];

    int bx = blockIdx.x;
    int t  = threadIdx.x;

    int kind, chunk, nchunks;
    if (bx < 2 * CV) { kind = bx / CV; chunk = bx % CV; nchunks = CV; }
    else             { kind = 2;       chunk = bx - 2 * CV; nchunks = CF; }
    int CP = (N + nchunks - 1) / nchunks;
    int n0 = chunk * CP;
    int n1 = min(N, n0 + CP);

    bool isFy = (kind == 2);
    float ta64 = isFy ? 0.f : (float)(kind * 64);

    float2 acc[4][8];
    for (int i = 0; i < 4; ++i)
        for (int j = 0; j < 8; ++j) acc[i][j] = make_float2(0.f, 0.f);

    int gy = t >> 4, gx = t & 15;

    for (int s = n0; s < n1; s += PB) {
        int cnt = min(PB, n1 - s);
        __syncthreads();
        if (t < cnt) {
            xs1[t] = x[2 * (s + t)];
            xs2[t] = x[2 * (s + t) + 1];
            yv[t]  = y[s + t];
        }
        __syncthreads();
        for (int v = t; v < cnt * 192; v += 256) {
            int pi = v / 192;
            int c  = v - pi * 192;
            int side = (c >= 64) ? 1 : 0;
            int i = side ? (c - 64) : c;
            float xval = side ? xs2[pi] : xs1[pi];
            float m, scale = 1.f;
            bool zero = false;
            if (!isFy) {
                m = side ? ((float)i - 63.f) : (ta64 + (float)i - 63.f);
                zero = (side && i == 127);   // circulant pad slot
            } else {
                m = 32.f - (float)i;
                zero = (side && i >= 64);
                if (!side) scale = yv[pi];
            }
            float2 g = phasef(xval, m);
            g.x *= scale; g.y *= scale;
            if (zero) g = make_float2(0.f, 0.f);
            hs[pi][c] = g;
        }
        __syncthreads();
        if (!isFy) {
            for (int p = 0; p < cnt; ++p) {
                float2 h1[4], h2[8];
                for (int i = 0; i < 4; ++i) h1[i] = hs[p][4 * gy + i];
                for (int j = 0; j < 8; ++j) h2[j] = hs[p][64 + 8 * gx + j];
                for (int i = 0; i < 4; ++i)
                    for (int j = 0; j < 8; ++j) cmac(acc[i][j], h1[i], h2[j]);
            }
        } else {
            for (int p = 0; p < cnt; ++p) {
                float2 h1[4], h2[4];
                for (int i = 0; i < 4; ++i) h1[i] = hs[p][4 * gy + i];
                for (int j = 0; j < 4; ++j) h2[j] = hs[p][64 + 4 * gx + j];
                for (int i = 0; i < 4; ++i)
                    for (int j = 0; j < 4; ++j) cmac(acc[i][j], h1[i], h2[j]);
            }
        }
    }
    __syncthreads();
    if (!isFy) {
        int ta = kind * 64;
        for (int i = 0; i < 4; ++i) {
            int ag = ta + 4 * gy + i;
            if (ag >= 127) continue;
            int q1 = (ag + 65) & 127;
            for (int j = 0; j < 8; ++j) {
                int bg = 8 * gx + j;
                if (bg >= 127) continue;
                int q2 = (bg + 65) & 127;
                atomicAdd(&vc[q1 * 128 + q2].x, (double)acc[i][j].x);
                atomicAdd(&vc[q1 * 128 + q2].y, (double)acc[i][j].y);
            }
        }
    } else {
        for (int i = 0; i < 4; ++i) {
            int a = 4 * gy + i;
            for (int j = 0; j < 4; ++j) {
                int b = 4 * gx + j;
                atomicAdd(&fy[a * 64 + b].x, (double)acc[i][j].x);
                atomicAdd(&fy[a * 64 + b].y, (double)acc[i][j].y);
            }
        }
    }
}

// ---------------------------------------------------------------------------
// 128-point fp64 DFT (matmul form) along rows / cols for Vf.
// ---------------------------------------------------------------------------
__global__ __launch_bounds__(128) void k_dft_rows(const double2* __restrict__ src,
                                                  double2* __restrict__ dst)
{
    __shared__ double2 u[128], tw[128];
    int r = blockIdx.x, t = threadIdx.x;
    { double sn, cs; sincospi(-(double)t / 64.0, &sn, &cs); tw[t] = make_double2(cs, sn); }
    u[t] = src[r * 128 + t];
    __syncthreads();
    double2 a = make_double2(0.0, 0.0);
    for (int j = 0; j < 128; ++j) dmac(a, u[j], tw[(j * t) & 127]);
    dst[r * 128 + t] = a;
}

__global__ __launch_bounds__(128) void k_dft_cols(const double2* __restrict__ src,
                                                  double2* __restrict__ dst)
{
    __shared__ double2 u[128], tw[128];
    int c = blockIdx.x, t = threadIdx.x;
    { double sn, cs; sincospi(-(double)t / 64.0, &sn, &cs); tw[t] = make_double2(cs, sn); }
    u[t] = src[t * 128 + c];
    __syncthreads();
    double2 a = make_double2(0.0, 0.0);
    for (int j = 0; j < 128; ++j) dmac(a, u[j], tw[(j * t) & 127]);
    dst[t * 128 + c] = a;
}

// ---------------------------------------------------------------------------
// CG init: r = b = ws*Fy, x = 0, scal[0] = <b,b>
// ---------------------------------------------------------------------------
__global__ __launch_bounds__(256) void k_init(const double2* __restrict__ fy,
                                              const float* __restrict__ wsv,
                                              double2* __restrict__ r,
                                              double2* __restrict__ xsol,
                                              double* __restrict__ scal)
{
    __shared__ double red[256];
    int idx = blockIdx.x * 256 + threadIdx.x;
    double2 f = fy[idx];
    double w = (double)wsv[idx];
    double2 b = make_double2(w * f.x, w * f.y);
    r[idx] = b;
    xsol[idx] = make_double2(0.0, 0.0);
    red[threadIdx.x] = b.x * b.x + b.y * b.y;
    __syncthreads();
    for (int sdv = 128; sdv > 0; sdv >>= 1) {
        if (threadIdx.x < sdv) red[threadIdx.x] += red[threadIdx.x + sdv];
        __syncthreads();
    }
    if (threadIdx.x == 0) atomicAdd(&scal[0], red[0]);
}

// ---------------------------------------------------------------------------
// CG stage 1 (row rr<64): p update (beta), z = ws*p, pad, forward row DFT.
// ---------------------------------------------------------------------------
__global__ __launch_bounds__(128) void k_cg1(const float* __restrict__ wsv,
                                             double2* __restrict__ p,
                                             const double2* __restrict__ r,
                                             double2* __restrict__ Z1,
                                             const double* __restrict__ scal, int it)
{
    __shared__ double2 u[128], tw[128];
    int rr = blockIdx.x, t = threadIdx.x;
    { double sn, cs; sincospi(-(double)t / 64.0, &sn, &cs); tw[t] = make_double2(cs, sn); }
    if (t < 64) {
        int idx = rr * 64 + t;
        double2 rv = r[idx];
        double2 pv;
        if (it == 0) pv = rv;
        else {
            double beta = scal[it] / (scal[it - 1] + 1e-30);
            double2 po = p[idx];
            pv = make_double2(rv.x + beta * po.x, rv.y + beta * po.y);
        }
        p[idx] = pv;
        double w = (double)wsv[idx];
        u[t] = make_double2(w * pv.x, w * pv.y);
    } else {
        u[t] = make_double2(0.0, 0.0);
    }
    __syncthreads();
    double2 a = make_double2(0.0, 0.0);
    for (int j = 0; j < 64; ++j) dmac(a, u[j], tw[(j * t) & 127]);
    Z1[rr * 128 + t] = a;
}

// ---------------------------------------------------------------------------
// CG stage 2 (col c): forward col DFT (rows>=64 zero), *Vf, inverse col DFT.
// ---------------------------------------------------------------------------
__global__ __launch_bounds__(128) void k_cg2(const double2* __restrict__ Z1,
                                             const double2* __restrict__ Vf,
                                             double2* __restrict__ Z2)
{
    __shared__ double2 u[128], tw[128], w[128];
    int c = blockIdx.x, t = threadIdx.x;
    { double sn, cs; sincospi(-(double)t / 64.0, &sn, &cs); tw[t] = make_double2(cs, sn); }
    u[t] = Z1[t * 128 + c];
    __syncthreads();
    double2 a = make_double2(0.0, 0.0);
    for (int j = 0; j < 64; ++j) dmac(a, u[j], tw[(j * t) & 127]);
    double2 vf = Vf[t * 128 + c];
    w[t] = make_double2(a.x * vf.x - a.y * vf.y, a.x * vf.y + a.y * vf.x);
    __syncthreads();
    if (t < 64) {
        double2 a2 = make_double2(0.0, 0.0);
        for (int k = 0; k < 128; ++k) dmacc(a2, w[k], tw[(t * k) & 127]);
        Z2[t * 128 + c] = a2;
    }
}

// ---------------------------------------------------------------------------
// CG stage 3 (row rr<64): inverse row DFT, /16384, Ap = ws*Tz + s2*p, <p,Ap>
// ---------------------------------------------------------------------------
__global__ __launch_bounds__(128) void k_cg3(const double2* __restrict__ Z2,
                                             const float* __restrict__ wsv,
                                             const double2* __restrict__ p,
                                             double2* __restrict__ Ap,
                                             const float* __restrict__ sig2,
                                             double* __restrict__ scal, int it)
{
    __shared__ double2 w[128], tw[128];
    __shared__ double red[128];
    int rr = blockIdx.x, t = threadIdx.x;
    { double sn, cs; sincospi(-(double)t / 64.0, &sn, &cs); tw[t] = make_double2(cs, sn); }
    w[t] = Z2[rr * 128 + t];
    __syncthreads();
    double dot = 0.0;
    if (t < 64) {
        double2 a = make_double2(0.0, 0.0);
        for (int k = 0; k < 128; ++k) dmacc(a, w[k], tw[(t * k) & 127]);
        const double inv = 1.0 / 16384.0;
        int idx = rr * 64 + t;
        double wv = (double)wsv[idx];
        double s2 = (double)sig2[0];
        double2 pv = p[idx];
        double2 ap = make_double2(wv * a.x * inv + s2 * pv.x,
                                  wv * a.y * inv + s2 * pv.y);
        Ap[idx] = ap;
        dot = pv.x * ap.x + pv.y * ap.y;
    }
    red[t] = dot;
    __syncthreads();
    for (int sdv = 64; sdv > 0; sdv >>= 1) {
        if (t < sdv) red[t] += red[t + sdv];
        __syncthreads();
    }
    if (t == 0) atomicAdd(&scal[64 + it], red[0]);
}

// ---------------------------------------------------------------------------
// CG stage 4: alpha; x += alpha p; r -= alpha Ap; scal[it+1]=<r,r>
// ---------------------------------------------------------------------------
__global__ __launch_bounds__(256) void k_cg4(double2* __restrict__ xsol,
                                             double2* __restrict__ r,
                                             const double2* __restrict__ p,
                                             const double2* __restrict__ Ap,
                                             double* __restrict__ scal, int it)
{
    __shared__ double red[256];
    int idx = blockIdx.x * 256 + threadIdx.x;
    double alpha = scal[it] / (scal[64 + it] + 1e-30);
    double2 pv = p[idx], av = Ap[idx], xv = xsol[idx], rv = r[idx];
    xv.x += alpha * pv.x; xv.y += alpha * pv.y;
    rv.x -= alpha * av.x; rv.y -= alpha * av.y;
    xsol[idx] = xv;
    r[idx] = rv;
    red[threadIdx.x] = rv.x * rv.x + rv.y * rv.y;
    __syncthreads();
    for (int sdv = 128; sdv > 0; sdv >>= 1) {
        if (threadIdx.x < sdv) red[threadIdx.x] += red[threadIdx.x + sdv];
        __syncthreads();
    }
    if (threadIdx.x == 0) atomicAdd(&scal[it + 1], red[0]);
}

// ---------------------------------------------------------------------------
// Evaluation: mu[b] = Re( sum_j e1[j] * sum_k alpha[j,k] e2[k] ),
// alpha = ws*xsol (fp32 in LDS); phases via fp64 sincospi/recurrence.
// ---------------------------------------------------------------------------
__global__ __launch_bounds__(64) void k_eval(const float* __restrict__ xnew,
                                             const float* __restrict__ wsv,
                                             const double2* __restrict__ xsol,
                                             float* __restrict__ out, int B)
{
    __shared__ float2 al[4096];
    int t = threadIdx.x;
    int b = blockIdx.x * 64 + t;
    for (int i = t; i < 4096; i += 64) {
        double2 xv = xsol[i];
        double w = (double)wsv[i];
        al[i] = make_float2((float)(w * xv.x), (float)(w * xv.y));
    }
    float x0 = 0.f, x1 = 0.f;
    if (b < B) { x0 = xnew[2 * b]; x1 = xnew[2 * b + 1]; }
    __syncthreads();
    double2 wstep; { double sn, cs; sincospi((double)x1, &sn, &cs); wstep = make_double2(cs, sn); }
    double mu = 0.0;
    for (int jg = 0; jg < 4; ++jg) {
        float2 tacc[16];
        for (int q = 0; q < 16; ++q) tacc[q] = make_float2(0.f, 0.f);
        double2 e2; { double sn, cs; sincospi(-32.0 * (double)x1, &sn, &cs); e2 = make_double2(cs, sn); }
        for (int k = 0; k < 64; ++k) {
            float2 e2f = make_float2((float)e2.x, (float)e2.y);
            for (int q = 0; q < 16; ++q) {
                int j = jg * 16 + q;
                cmac(tacc[q], al[j * 64 + k], e2f);
            }
            e2 = make_double2(e2.x * wstep.x - e2.y * wstep.y,
                              e2.x * wstep.y + e2.y * wstep.x);
        }
        for (int q = 0; q < 16; ++q) {
            int j = jg * 16 + q;
            double sn, cs;
            sincospi((double)x0 * (double)(j - 32), &sn, &cs);
            mu += cs * (double)tacc[q].x - sn * (double)tacc[q].y;
        }
    }
    if (b < B) out[b] = (float)mu;
}

// ---------------------------------------------------------------------------

extern "C" void kernel_launch(void* const* d_in, const int* in_sizes, int n_in,
                              void* d_out, int out_size, void* d_ws, size_t ws_size,
                              hipStream_t stream)
{
    const float* x    = (const float*)d_in[0];
    const float* y    = (const float*)d_in[1];
    const float* xnew = (const float*)d_in[2];
    const float* wsv  = (const float*)d_in[3];
    const float* sig2 = (const float*)d_in[4];
    int N = in_sizes[1];
    int B = in_sizes[2] / 2;

    char* base = (char*)d_ws;
    double2* vc   = (double2*)(base + 0);         // 128x128 circulant v
    double2* Vf   = (double2*)(base + 262144);    // FFT2(vc)
    double2* bufA = (double2*)(base + 524288);    // row-DFT intermediate
    double2* Z1   = (double2*)(base + 786432);    // 128x128
    double2* Z2   = (double2*)(base + 1048576);   // 64x128
    double2* p    = (double2*)(base + 1179648);
    double2* r    = (double2*)(base + 1245184);
    double2* xsol = (double2*)(base + 1310720);
    double2* Ap   = (double2*)(base + 1376256);
    double2* fy   = (double2*)(base + 1441792);
    double*  scal = (double*)(base + 1507328);    // [0..63]=rz, [64..127]=pAp

    hipMemsetAsync(d_ws, 0, 1508352, stream);

    k_outer<<<NBLK, 256, 0, stream>>>(x, y, vc, fy, N);
    k_dft_rows<<<128, 128, 0, stream>>>(vc, bufA);
    k_dft_cols<<<128, 128, 0, stream>>>(bufA, Vf);
    k_init<<<16, 256, 0, stream>>>(fy, wsv, r, xsol, scal);

    for (int it = 0; it < 50; ++it) {
        k_cg1<<<64, 128, 0, stream>>>(wsv, p, r, Z1, scal, it);
        k_cg2<<<128, 128, 0, stream>>>(Z1, Vf, Z2);
        k_cg3<<<64, 128, 0, stream>>>(Z2, wsv, p, Ap, sig2, scal, it);
        k_cg4<<<16, 256, 0, stream>>>(xsol, r, p, Ap, scal, it);
    }

    k_eval<<<(B + 63) / 64, 64, 0, stream>>>(xnew, wsv, xsol, (float*)d_out, B);
}